// Round 5
// baseline (34.892 us; speedup 1.0000x reference)
//
#include <hip/hip_runtime.h>
#include <stdint.h>

#define BB 512
#define NN 8192
#define KK 16
#define HH 16

typedef _Float16 f16;
typedef _Float16 f16x4 __attribute__((ext_vector_type(4)));
typedef float f32x4 __attribute__((ext_vector_type(4)));
typedef uint32_t u32x2 __attribute__((ext_vector_type(2)));

// ---------------------------------------------------------------------------
// Kernel 1: pack signs of x (+-1) into transposed-word bitmask.
// xpT[j*16 + w] bit i = (x[(w*32+i)*N + j] > 0).  512 KB, L2-resident.
// One j-row (16 words = 64B = all 512 b) is exactly one cache line.
// ---------------------------------------------------------------------------
__global__ __launch_bounds__(256) void pack_kernel(const float* __restrict__ x,
                                                   uint32_t* __restrict__ xpT) {
    const int j = blockIdx.x * 256 + threadIdx.x;
    const int w = blockIdx.y;
    uint32_t word = 0u;
#pragma unroll
    for (int i = 0; i < 32; ++i)
        word |= (x[(size_t)(w * 32 + i) * NN + j] > 0.0f ? 1u : 0u) << i;
    xpT[(size_t)j * 16 + w] = word;
}

// ---------------------------------------------------------------------------
// Kernel 2: grid = 512 blocks (one per 16-n stripe), 512 threads = 8 waves.
// Each wave owns 2 n x ALL 512 b  ->  W1 read exactly once, each n's sign
// row (1 KB, 16 lines) fetched exactly once with fully-lined loads
// (lane (lg,l15) loads xpT[j(k=4q+lg)*16 + l15] : 4 whole 64B lines/instr).
// Words staged to wave-private LDS [w][k] (pad 20), read back per MFMA as
// one broadcast ds_read_b128.  B-frag = bit -> +-1.0 f16 (~14 VALU).
// One mfma_f32_16x16x16_f16 per 16-b tile (K=16 exact).  Stage 2 = 4 fma +
// 2 shfl + sigmoid.  Output transpose fused via tile[512][20]; final stores
// are full 64B lines of out[b][n0..n0+15].
// ---------------------------------------------------------------------------
__global__ __launch_bounds__(512, 4) void mfma_kernel(
    const uint32_t* __restrict__ xpT, const int* __restrict__ neighs,
    const float* __restrict__ W1, const float* __restrict__ b1,
    const float* __restrict__ W2, const float* __restrict__ b2,
    float* __restrict__ out) {
    __shared__ __align__(16) uint32_t wbuf[8][2][16 * 20];  // [wave][ni][w*20+k]
    __shared__ __align__(16) float tile[512][20];           // [b][n_local]

    const int tid = threadIdx.x;
    const int wv  = __builtin_amdgcn_readfirstlane(tid >> 6);  // 0..7
    const int l   = tid & 63;
    const int l15 = l & 15;
    const int lg  = l >> 4;              // 0..3
    const int n0  = blockIdx.x * 16;

#pragma unroll
    for (int ni = 0; ni < 2; ++ni) {
        const int n = n0 + wv * 2 + ni;
        uint32_t* wb = &wbuf[wv][ni][0];

        // ---- stage this n's full sign row: 16 k x 16 w words ----
#pragma unroll
        for (int q = 0; q < 4; ++q) {
            const int k = q * 4 + lg;
            const int j = neighs[n * KK + k];
            wb[l15 * 20 + k] = xpT[(size_t)j * 16 + l15];
        }

        // ---- A-frag: A[h=l15][k=lg*4+i] = W1[n][k][h] ----
        const float* W1n = W1 + (size_t)n * (KK * HH) + lg * 4 * HH + l15;
        f16x4 a;
#pragma unroll
        for (int i = 0; i < 4; ++i) a[i] = (f16)W1n[i * HH];

        const float4 b1v = *(const float4*)(b1 + (size_t)n * HH + lg * 4);
        const f32x4 cinit = {b1v.x, b1v.y, b1v.z, b1v.w};
        const float4 w2v = *(const float4*)(W2 + (size_t)n * HH + lg * 4);
        const float b2n = b2[n];

#pragma unroll
        for (int tb = 0; tb < 32; ++tb) {       // 32 b-tiles of 16
            const int wg  = tb >> 1;
            const int pos = (tb & 1) * 16 + l15;  // bit index within word
            const uint4 wk = *(const uint4*)&wb[wg * 20 + lg * 4];
            // bit=1 -> +1.0f16 (0x3C00), bit=0 -> -1.0f16 (0xBC00)
            const uint32_t d0 = 0xBC00BC00u ^ (((wk.x >> pos) & 1u) << 15) ^
                                (((wk.y >> pos) & 1u) << 31);
            const uint32_t d1 = 0xBC00BC00u ^ (((wk.z >> pos) & 1u) << 15) ^
                                (((wk.w >> pos) & 1u) << 31);
            const u32x2 bd = {d0, d1};
            const f16x4 bfr = __builtin_bit_cast(f16x4, bd);

            const f32x4 acc =
                __builtin_amdgcn_mfma_f32_16x16x16f16(a, bfr, cinit, 0, 0, 0);

            float z = fmaf(fmaxf(acc[0], 0.f), w2v.x,
                      fmaf(fmaxf(acc[1], 0.f), w2v.y,
                      fmaf(fmaxf(acc[2], 0.f), w2v.z,
                           fmaxf(acc[3], 0.f) * w2v.w)));
            z += __shfl_xor(z, 16);
            z += __shfl_xor(z, 32);
            z += b2n;
            const float r = 1.0f / (1.0f + __expf(-z));
            if (l < 16) tile[tb * 16 + l15][wv * 2 + ni] = r;
        }
    }
    __syncthreads();

    // full-line stores: 4 lanes cover one 64B row of out[b][n0..n0+15]
#pragma unroll
    for (int p = 0; p < 4; ++p) {
        const int row = (tid >> 2) + p * 128;
        const int c   = (tid & 3) * 4;
        const float4 v = *(const float4*)&tile[row][c];
        *(float4*)(out + (size_t)row * NN + n0 + c) = v;
    }
}

// ---------------------------------------------------------------------------
// Fallback scalar kernel (only if workspace is too small).
// ---------------------------------------------------------------------------
__global__ __launch_bounds__(512) void scalar_kernel(
    const float* __restrict__ x, const int* __restrict__ neighs,
    const float* __restrict__ W1, const float* __restrict__ b1,
    const float* __restrict__ W2, const float* __restrict__ b2,
    float* __restrict__ outp) {
    const int n = blockIdx.x;
    const int b = threadIdx.x;
    const int* nb = neighs + n * KK;
    const float* W1n = W1 + (size_t)n * KK * HH;
    const float* b1n = b1 + (size_t)n * HH;
    const float* W2n = W2 + (size_t)n * HH;

    float s[KK];
#pragma unroll
    for (int k = 0; k < KK; ++k) s[k] = x[(size_t)b * NN + nb[k]];

    float acc[HH];
#pragma unroll
    for (int h = 0; h < HH; ++h) acc[h] = b1n[h];
#pragma unroll
    for (int k = 0; k < KK; ++k)
#pragma unroll
        for (int h = 0; h < HH; ++h)
            acc[h] = fmaf(s[k], W1n[k * HH + h], acc[h]);

    float z = b2[n];
#pragma unroll
    for (int h = 0; h < HH; ++h)
        z = fmaf(fmaxf(acc[h], 0.0f), W2n[h], z);
    outp[(size_t)b * NN + n] = 1.0f / (1.0f + __expf(-z));
}

extern "C" void kernel_launch(void* const* d_in, const int* in_sizes, int n_in,
                              void* d_out, int out_size, void* d_ws, size_t ws_size,
                              hipStream_t stream) {
    const float* x      = (const float*)d_in[0];
    const int*   neighs = (const int*)d_in[1];
    const float* W1     = (const float*)d_in[2];
    const float* b1     = (const float*)d_in[3];
    const float* W2     = (const float*)d_in[4];
    const float* b2     = (const float*)d_in[5];
    float* out = (float*)d_out;

    const size_t pack_bytes = (size_t)NN * 16 * sizeof(uint32_t);  // 512 KB

    if (ws_size >= pack_bytes) {
        uint32_t* xpT = (uint32_t*)d_ws;
        pack_kernel<<<dim3(NN / 256, BB / 32), 256, 0, stream>>>(x, xpT);
        mfma_kernel<<<dim3(NN / 16), 512, 0, stream>>>(
            xpT, neighs, W1, b1, W2, b2, out);
    } else {
        scalar_kernel<<<NN, BB, 0, stream>>>(x, neighs, W1, b1, W2, b2, out);
    }
}

// Round 6
// 33.118 us; speedup vs baseline: 1.0536x; 1.0536x over previous
//
#include <hip/hip_runtime.h>
#include <stdint.h>

#define BB 512
#define NN 8192
#define KK 16
#define HH 16

typedef _Float16 f16;
typedef _Float16 f16x4 __attribute__((ext_vector_type(4)));
typedef float f32x4 __attribute__((ext_vector_type(4)));

// ---------------------------------------------------------------------------
// Prep kernel (fused):
//  blocks [0,512):    pack signs of x (+-1) into transposed-word bitmask.
//                     xpT[j*16+w] bit i = (x[(w*32+i)*N+j] > 0).  512 KB.
//  blocks [512,2560): convert W1 -> f16 A-fragment order:
//                     W1f[n*64 + l] = {W1[n][4*(l>>4)+i][l&15]} i=0..3 (8B).
// ---------------------------------------------------------------------------
__global__ __launch_bounds__(256) void prep_kernel(
    const float* __restrict__ x, const float* __restrict__ W1,
    uint32_t* __restrict__ xpT, uint2* __restrict__ W1f) {
    const int bid = blockIdx.x;
    const int tid = threadIdx.x;
    if (bid < 512) {
        const int j = (bid & 31) * 256 + tid;
        const int w = bid >> 5;
        uint32_t word = 0u;
#pragma unroll
        for (int i = 0; i < 32; ++i)
            word |= (x[(size_t)(w * 32 + i) * NN + j] > 0.0f ? 1u : 0u) << i;
        xpT[(size_t)j * 16 + w] = word;
    } else {
        const int n   = (bid - 512) * 4 + (tid >> 6);
        const int l   = tid & 63;
        const int l15 = l & 15;
        const int lg  = l >> 4;
        const float* W1n = W1 + (size_t)n * (KK * HH) + lg * 4 * HH + l15;
        f16x4 a;
#pragma unroll
        for (int i = 0; i < 4; ++i) a[i] = (f16)W1n[i * HH];
        W1f[(size_t)n * 64 + l] = __builtin_bit_cast(uint2, a);
    }
}

// ---------------------------------------------------------------------------
// Main kernel: grid (512, 2); block = 16n x 256b, 512 thr = 8 waves;
// wave = 2n x 256b = 32 MFMAs.  All global latency issued up front:
// 2 sign-gathers (dwordx2/lane), 2 A-frags (8B/lane coalesced), 2 epilogue
// param sets.  Sign words staged in wave-private LDS [w][k] (stride 20),
// read back per MFMA-pair as one broadcast ds_read_b128.  B-frag = bit ->
// +-1.0 f16 via shift/xor into 0xBC00BC00.  mfma_f32_16x16x16_f16 (K=16
// exact).  Stage 2 = 4 fma + 2 shfl + sigmoid.  Output transpose fused via
// tile[256][20]; stores are full 64B lines of out[b][n0..n0+15].
// LDS ~31.5 KB, target 64 VGPR -> 4 blocks/CU, 8 waves/SIMD.
// ---------------------------------------------------------------------------
__global__ __launch_bounds__(512, 8) void mfma_kernel(
    const uint32_t* __restrict__ xpT, const uint2* __restrict__ W1f,
    const int* __restrict__ neighs, const float* __restrict__ b1,
    const float* __restrict__ W2, const float* __restrict__ b2,
    float* __restrict__ out) {
    __shared__ __align__(16) uint32_t wbuf[8][2][8 * 20];  // [wave][ni][w*20+k]
    __shared__ __align__(16) float tile[256][20];          // [b_local][n_local]

    const int tid = threadIdx.x;
    const int wv  = tid >> 6;        // 0..7
    const int l   = tid & 63;
    const int l15 = l & 15;
    const int lg  = l >> 4;          // 0..3
    const int n0  = blockIdx.x * 16;
    const int b0  = blockIdx.y * 256;
    const int w0  = blockIdx.y * 8;  // word base for this b-half

    const int nA = n0 + wv * 2;      // ni=0
    const int nB = nA + 1;           // ni=1

    // ---- issue ALL global loads up front ----
    const int j0 = neighs[nA * KK + l15];   // 64B broadcast load
    const int j1 = neighs[nB * KK + l15];
    const uint2 g0 = *(const uint2*)&xpT[(size_t)j0 * 16 + w0 + lg * 2];
    const uint2 g1 = *(const uint2*)&xpT[(size_t)j1 * 16 + w0 + lg * 2];
    const uint2 af0u = W1f[(size_t)nA * 64 + l];
    const uint2 af1u = W1f[(size_t)nB * 64 + l];
    const float4 b1v0 = *(const float4*)(b1 + (size_t)nA * HH + lg * 4);
    const float4 b1v1 = *(const float4*)(b1 + (size_t)nB * HH + lg * 4);
    const float4 w2v0 = *(const float4*)(W2 + (size_t)nA * HH + lg * 4);
    const float4 w2v1 = *(const float4*)(W2 + (size_t)nB * HH + lg * 4);
    const float b2n0 = b2[nA];
    const float b2n1 = b2[nB];

    // ---- stage sign words: layout [w][k], stride 20 (2-way banks = free) ----
    wbuf[wv][0][(2 * lg) * 20 + l15]     = g0.x;
    wbuf[wv][0][(2 * lg + 1) * 20 + l15] = g0.y;
    wbuf[wv][1][(2 * lg) * 20 + l15]     = g1.x;
    wbuf[wv][1][(2 * lg + 1) * 20 + l15] = g1.y;

#pragma unroll
    for (int ni = 0; ni < 2; ++ni) {
        const uint2 afu = ni ? af1u : af0u;
        const f16x4 a = __builtin_bit_cast(f16x4, afu);
        const float4 b1v = ni ? b1v1 : b1v0;
        const float4 w2v = ni ? w2v1 : w2v0;
        const float b2n  = ni ? b2n1 : b2n0;
        const f32x4 cinit = {b1v.x, b1v.y, b1v.z, b1v.w};
        const uint32_t* wb = &wbuf[wv][ni][0];
        const int nloc = wv * 2 + ni;

#pragma unroll
        for (int wg = 0; wg < 8; ++wg) {     // 8 word-groups x 2 tiles
            const uint4 wk = *(const uint4*)&wb[wg * 20 + lg * 4];
            const uint32_t sx = wk.x >> l15, sy = wk.y >> l15,
                           sz = wk.z >> l15, sw = wk.w >> l15;
#pragma unroll
            for (int h2 = 0; h2 < 2; ++h2) {
                const int sh = h2 * 16;
                // bit=1 -> +1.0f16 (0x3C00), bit=0 -> -1.0f16 (0xBC00)
                const uint32_t d0 = 0xBC00BC00u ^ (((sx >> sh) & 1u) << 15) ^
                                    ((sy >> sh) << 31);
                const uint32_t d1 = 0xBC00BC00u ^ (((sz >> sh) & 1u) << 15) ^
                                    ((sw >> sh) << 31);
                uint2 bdu; bdu.x = d0; bdu.y = d1;
                const f16x4 bfr = __builtin_bit_cast(f16x4, bdu);

                const f32x4 acc = __builtin_amdgcn_mfma_f32_16x16x16f16(
                    a, bfr, cinit, 0, 0, 0);

                float z = fmaf(fmaxf(acc[0], 0.f), w2v.x,
                          fmaf(fmaxf(acc[1], 0.f), w2v.y,
                          fmaf(fmaxf(acc[2], 0.f), w2v.z,
                               fmaxf(acc[3], 0.f) * w2v.w)));
                z += __shfl_xor(z, 16);
                z += __shfl_xor(z, 32);
                z += b2n;
                const float r = 1.0f / (1.0f + __expf(-z));
                const int tb = wg * 2 + h2;
                if (l < 16) tile[tb * 16 + l15][nloc] = r;
            }
        }
    }
    __syncthreads();

    // full-line stores: 4 lanes cover one 64B row of out[b][n0..n0+15]
#pragma unroll
    for (int p = 0; p < 2; ++p) {
        const int row = (tid >> 2) + p * 128;
        const int c   = (tid & 3) * 4;
        const float4 v = *(const float4*)&tile[row][c];
        *(float4*)(out + (size_t)(b0 + row) * NN + n0 + c) = v;
    }
}

// ---------------------------------------------------------------------------
// Fallback scalar kernel (only if workspace is too small).
// ---------------------------------------------------------------------------
__global__ __launch_bounds__(512) void scalar_kernel(
    const float* __restrict__ x, const int* __restrict__ neighs,
    const float* __restrict__ W1, const float* __restrict__ b1,
    const float* __restrict__ W2, const float* __restrict__ b2,
    float* __restrict__ outp) {
    const int n = blockIdx.x;
    const int b = threadIdx.x;
    const int* nb = neighs + n * KK;
    const float* W1n = W1 + (size_t)n * KK * HH;
    const float* b1n = b1 + (size_t)n * HH;
    const float* W2n = W2 + (size_t)n * HH;

    float s[KK];
#pragma unroll
    for (int k = 0; k < KK; ++k) s[k] = x[(size_t)b * NN + nb[k]];

    float acc[HH];
#pragma unroll
    for (int h = 0; h < HH; ++h) acc[h] = b1n[h];
#pragma unroll
    for (int k = 0; k < KK; ++k)
#pragma unroll
        for (int h = 0; h < HH; ++h)
            acc[h] = fmaf(s[k], W1n[k * HH + h], acc[h]);

    float z = b2[n];
#pragma unroll
    for (int h = 0; h < HH; ++h)
        z = fmaf(fmaxf(acc[h], 0.0f), W2n[h], z);
    outp[(size_t)b * NN + n] = 1.0f / (1.0f + __expf(-z));
}

extern "C" void kernel_launch(void* const* d_in, const int* in_sizes, int n_in,
                              void* d_out, int out_size, void* d_ws, size_t ws_size,
                              hipStream_t stream) {
    const float* x      = (const float*)d_in[0];
    const int*   neighs = (const int*)d_in[1];
    const float* W1     = (const float*)d_in[2];
    const float* b1     = (const float*)d_in[3];
    const float* W2     = (const float*)d_in[4];
    const float* b2     = (const float*)d_in[5];
    float* out = (float*)d_out;

    const size_t pack_bytes = (size_t)NN * 16 * sizeof(uint32_t);  // 512 KB
    const size_t w1f_bytes  = (size_t)NN * 64 * sizeof(uint2);     // 4 MB

    if (ws_size >= pack_bytes + w1f_bytes) {
        uint32_t* xpT = (uint32_t*)d_ws;
        uint2* W1f    = (uint2*)((char*)d_ws + pack_bytes);
        prep_kernel<<<512 + NN / 4, 256, 0, stream>>>(x, W1, xpT, W1f);
        mfma_kernel<<<dim3(NN / 16, BB / 256), 512, 0, stream>>>(
            xpT, W1f, neighs, b1, W2, b2, out);
    } else {
        scalar_kernel<<<NN, BB, 0, stream>>>(x, neighs, W1, b1, W2, b2, out);
    }
}

// Round 7
// 26.612 us; speedup vs baseline: 1.3111x; 1.2445x over previous
//
#include <hip/hip_runtime.h>
#include <stdint.h>

#define BB 512
#define NN 8192
#define KK 16
#define HH 16

typedef _Float16 f16;
typedef _Float16 f16x4 __attribute__((ext_vector_type(4)));
typedef float f32x4 __attribute__((ext_vector_type(4)));

// ---------------------------------------------------------------------------
// Prep kernel (fused):
//  blocks [0,512):    pack signs of x (+-1) into transposed-word bitmask.
//                     xpT[j*16+w] bit i = (x[(w*32+i)*N+j] > 0).  512 KB.
//  blocks [512,2560): convert W1 -> f16 A-fragment order:
//                     W1f[n*64 + l] = {W1[n][4*(l>>4)+i][l&15]} i=0..3 (8B).
// ---------------------------------------------------------------------------
__global__ __launch_bounds__(256) void prep_kernel(
    const float* __restrict__ x, const float* __restrict__ W1,
    uint32_t* __restrict__ xpT, uint2* __restrict__ W1f) {
    const int bid = blockIdx.x;
    const int tid = threadIdx.x;
    if (bid < 512) {
        const int j = (bid & 31) * 256 + tid;
        const int w = bid >> 5;
        uint32_t word = 0u;
#pragma unroll
        for (int i = 0; i < 32; ++i)
            word |= (x[(size_t)(w * 32 + i) * NN + j] > 0.0f ? 1u : 0u) << i;
        xpT[(size_t)j * 16 + w] = word;
    } else {
        const int n   = (bid - 512) * 4 + (tid >> 6);
        const int l   = tid & 63;
        const int l15 = l & 15;
        const int lg  = l >> 4;
        const float* W1n = W1 + (size_t)n * (KK * HH) + lg * 4 * HH + l15;
        f16x4 a;
#pragma unroll
        for (int i = 0; i < 4; ++i) a[i] = (f16)W1n[i * HH];
        W1f[(size_t)n * 64 + l] = __builtin_bit_cast(uint2, a);
    }
}

// ---------------------------------------------------------------------------
// Main kernel: grid (512, 2); block = 16n x 256b, 512 thr = 8 waves;
// wave = 2n x 256b = 32 MFMAs.  Global latency issued up front (sign-word
// gathers dwordx2/lane, A-frags 8B/lane).  Sign words in wave-private LDS
// [w][k] stride 20, re-staged per ni (no barriers).  B-frag = bit -> +-1.0
// f16 via shift/xor into 0xBC00BC00.  mfma_f32_16x16x16_f16 (K=16 exact).
// Epilogue restructured for density: per MFMA only an 8-op relu-dot ->
// zp written to LDS zbuf; per 4-tile group ONE dense pass (64 lanes = 64
// outputs): ds_read_b128 + 3 adds + rcpf(1+expf) -- no shfl, no fp32 div,
// off the MFMA dependence chain.  Output transpose fused via tile[256][20];
// stores are full 64B lines.  LDS 33.8 KB -> 4 blocks/CU, 8 waves/SIMD.
// ---------------------------------------------------------------------------
__global__ __launch_bounds__(512, 8) void mfma_kernel(
    const uint32_t* __restrict__ xpT, const uint2* __restrict__ W1f,
    const int* __restrict__ neighs, const float* __restrict__ b1,
    const float* __restrict__ W2, const float* __restrict__ b2,
    float* __restrict__ out) {
    __shared__ __align__(16) uint32_t wbuf[8][8 * 20];  // [wave][w*20+k]
    __shared__ __align__(16) float zbuf[8][64][4];      // [wave][t*16+b16][lg]
    __shared__ __align__(16) float tile[256][20];       // [b_local][n_local]

    const int tid = threadIdx.x;
    const int wv  = tid >> 6;        // 0..7
    const int l   = tid & 63;
    const int l15 = l & 15;
    const int lg  = l >> 4;          // 0..3
    const int n0  = blockIdx.x * 16;
    const int b0  = blockIdx.y * 256;
    const int w0  = blockIdx.y * 8;  // word base for this b-half

    const int nA = n0 + wv * 2;
    const int nB = nA + 1;

    // ---- issue latency-critical global loads up front ----
    const int j0 = neighs[nA * KK + l15];   // 64B broadcast load
    const int j1 = neighs[nB * KK + l15];
    const uint2 g0 = *(const uint2*)&xpT[(size_t)j0 * 16 + w0 + lg * 2];
    const uint2 g1 = *(const uint2*)&xpT[(size_t)j1 * 16 + w0 + lg * 2];
    const uint2 af0u = W1f[(size_t)nA * 64 + l];
    const uint2 af1u = W1f[(size_t)nB * 64 + l];

#pragma unroll
    for (int ni = 0; ni < 2; ++ni) {
        const int n = ni ? nB : nA;
        const uint2 g = ni ? g1 : g0;
        const f16x4 a = __builtin_bit_cast(f16x4, ni ? af1u : af0u);
        const int nloc = wv * 2 + ni;

        // stage this ni's sign words (wave-private; reused buffer, no barrier)
        wbuf[wv][(2 * lg) * 20 + l15]     = g.x;
        wbuf[wv][(2 * lg + 1) * 20 + l15] = g.y;

        const float4 b1v = *(const float4*)(b1 + (size_t)n * HH + lg * 4);
        const f32x4 cinit = {b1v.x, b1v.y, b1v.z, b1v.w};
        const float4 w2v = *(const float4*)(W2 + (size_t)n * HH + lg * 4);
        const float b2n = b2[n];

#pragma unroll
        for (int g4 = 0; g4 < 4; ++g4) {   // 4 groups x 4 tiles (2 word-grps)
#pragma unroll
            for (int t = 0; t < 4; ++t) {
                const int tb = g4 * 4 + t;
                const int wg = tb >> 1;
                const uint4 wk = *(const uint4*)&wbuf[wv][wg * 20 + lg * 4];
                const int pos = (tb & 1) * 16 + l15;  // bit index within word
                // bit=1 -> +1.0f16 (0x3C00), bit=0 -> -1.0f16 (0xBC00)
                const uint32_t d0 = 0xBC00BC00u ^ (((wk.x >> pos) & 1u) << 15) ^
                                    ((wk.y >> pos) << 31);
                const uint32_t d1 = 0xBC00BC00u ^ (((wk.z >> pos) & 1u) << 15) ^
                                    ((wk.w >> pos) << 31);
                uint2 bdu; bdu.x = d0; bdu.y = d1;
                const f16x4 bfr = __builtin_bit_cast(f16x4, bdu);

                const f32x4 acc = __builtin_amdgcn_mfma_f32_16x16x16f16(
                    a, bfr, cinit, 0, 0, 0);

                // relu-dot partial: zp(lg, b=l15) = sum_r relu(acc)*w2
                const float zp =
                    fmaf(fmaxf(acc[0], 0.f), w2v.x,
                    fmaf(fmaxf(acc[1], 0.f), w2v.y,
                    fmaf(fmaxf(acc[2], 0.f), w2v.z,
                         fmaxf(acc[3], 0.f) * w2v.w)));
                zbuf[wv][t * 16 + l15][lg] = zp;
            }
            // dense pass: 64 lanes = 64 outputs of this 4-tile group
            const f32x4 v = *(const f32x4*)&zbuf[wv][l][0];
            const float z = (v[0] + v[1]) + (v[2] + v[3]) + b2n;
            const float r = __builtin_amdgcn_rcpf(1.0f + __expf(-z));
            tile[g4 * 64 + l][nloc] = r;
        }
    }
    __syncthreads();

    // full-line stores: 4 lanes cover one 64B row of out[b][n0..n0+15]
#pragma unroll
    for (int p = 0; p < 2; ++p) {
        const int row = (tid >> 2) + p * 128;
        const int c   = (tid & 3) * 4;
        const float4 v = *(const float4*)&tile[row][c];
        *(float4*)(out + (size_t)(b0 + row) * NN + n0 + c) = v;
    }
}

// ---------------------------------------------------------------------------
// Fallback scalar kernel (only if workspace is too small).
// ---------------------------------------------------------------------------
__global__ __launch_bounds__(512) void scalar_kernel(
    const float* __restrict__ x, const int* __restrict__ neighs,
    const float* __restrict__ W1, const float* __restrict__ b1,
    const float* __restrict__ W2, const float* __restrict__ b2,
    float* __restrict__ outp) {
    const int n = blockIdx.x;
    const int b = threadIdx.x;
    const int* nb = neighs + n * KK;
    const float* W1n = W1 + (size_t)n * KK * HH;
    const float* b1n = b1 + (size_t)n * HH;
    const float* W2n = W2 + (size_t)n * HH;

    float s[KK];
#pragma unroll
    for (int k = 0; k < KK; ++k) s[k] = x[(size_t)b * NN + nb[k]];

    float acc[HH];
#pragma unroll
    for (int h = 0; h < HH; ++h) acc[h] = b1n[h];
#pragma unroll
    for (int k = 0; k < KK; ++k)
#pragma unroll
        for (int h = 0; h < HH; ++h)
            acc[h] = fmaf(s[k], W1n[k * HH + h], acc[h]);

    float z = b2[n];
#pragma unroll
    for (int h = 0; h < HH; ++h)
        z = fmaf(fmaxf(acc[h], 0.0f), W2n[h], z);
    outp[(size_t)b * NN + n] = 1.0f / (1.0f + __expf(-z));
}

extern "C" void kernel_launch(void* const* d_in, const int* in_sizes, int n_in,
                              void* d_out, int out_size, void* d_ws, size_t ws_size,
                              hipStream_t stream) {
    const float* x      = (const float*)d_in[0];
    const int*   neighs = (const int*)d_in[1];
    const float* W1     = (const float*)d_in[2];
    const float* b1     = (const float*)d_in[3];
    const float* W2     = (const float*)d_in[4];
    const float* b2     = (const float*)d_in[5];
    float* out = (float*)d_out;

    const size_t pack_bytes = (size_t)NN * 16 * sizeof(uint32_t);  // 512 KB
    const size_t w1f_bytes  = (size_t)NN * 64 * sizeof(uint2);     // 4 MB

    if (ws_size >= pack_bytes + w1f_bytes) {
        uint32_t* xpT = (uint32_t*)d_ws;
        uint2* W1f    = (uint2*)((char*)d_ws + pack_bytes);
        prep_kernel<<<512 + NN / 4, 256, 0, stream>>>(x, W1, xpT, W1f);
        mfma_kernel<<<dim3(NN / 16, BB / 256), 512, 0, stream>>>(
            xpT, W1f, neighs, b1, W2, b2, out);
    } else {
        scalar_kernel<<<NN, BB, 0, stream>>>(x, neighs, W1, b1, W2, b2, out);
    }
}